// Round 2
// baseline (677.954 us; speedup 1.0000x reference)
//
#include <hip/hip_runtime.h>

// TransformerBlock: B=8, S=1024, D=1024, H=16, HD=64
// Pipeline: LN1 -> QKV GEMM -> causal flash attn -> proj(+resid) -> LN2
//           -> MLP1(+gelu) -> MLP2(+resid -> d_out)
// All GEMMs: bf16 MFMA 16x16x32, fp32 accumulate.

#define DEV static __device__ __forceinline__

typedef __attribute__((ext_vector_type(8))) __bf16 bf16x8;
typedef __attribute__((ext_vector_type(4))) float f32x4;

DEV ushort f2bf(float f) {
  union { float f; unsigned u; } c; c.f = f;
  unsigned r = (c.u + 0x7FFFu + ((c.u >> 16) & 1u)) >> 16;
  return (ushort)r;
}

DEV float geluf(float v) {
  return 0.5f * v * (1.0f + erff(v * 0.70710678118654752f));
}

// ---------------- LayerNorm (f32 in -> bf16 out), one block per row ----------------
__global__ __launch_bounds__(256)
void ln_bf16_kernel(const float* __restrict__ x, const float* __restrict__ g,
                    const float* __restrict__ bb, ushort* __restrict__ out)
{
  const int row = blockIdx.x, tid = threadIdx.x;
  const float4 v = ((const float4*)x)[row * 256 + tid];
  float s = v.x + v.y + v.z + v.w;
  float sq = v.x * v.x + v.y * v.y + v.z * v.z + v.w * v.w;
#pragma unroll
  for (int off = 32; off >= 1; off >>= 1) {
    s += __shfl_xor(s, off, 64);
    sq += __shfl_xor(sq, off, 64);
  }
  __shared__ float ps[4], pq[4];
  if ((tid & 63) == 0) { ps[tid >> 6] = s; pq[tid >> 6] = sq; }
  __syncthreads();
  s = ps[0] + ps[1] + ps[2] + ps[3];
  sq = pq[0] + pq[1] + pq[2] + pq[3];
  const float mu = s * (1.0f / 1024.0f);
  const float rstd = rsqrtf(sq * (1.0f / 1024.0f) - mu * mu + 1e-5f);
  const float4 gv = ((const float4*)g)[tid];
  const float4 bv = ((const float4*)bb)[tid];
  ushort4 o;
  o.x = f2bf((v.x - mu) * rstd * gv.x + bv.x);
  o.y = f2bf((v.y - mu) * rstd * gv.y + bv.y);
  o.z = f2bf((v.z - mu) * rstd * gv.z + bv.z);
  o.w = f2bf((v.w - mu) * rstd * gv.w + bv.w);
  ((ushort4*)out)[row * 256 + tid] = o;
}

// ---------------- transpose + f32->bf16: out[n*K+k] = bf16(in[k*N+n]) ----------------
__global__ __launch_bounds__(256)
void tcvt_kernel(const float* __restrict__ in, ushort* __restrict__ out, int K, int N)
{
  __shared__ float tile[32][33];
  const int tx = threadIdx.x & 31, ty = threadIdx.x >> 5;  // ty 0..7
  const int n0 = blockIdx.x * 32, k0 = blockIdx.y * 32;
#pragma unroll
  for (int j = 0; j < 4; ++j)
    tile[ty + j * 8][tx] = in[(size_t)(k0 + ty + j * 8) * N + n0 + tx];
  __syncthreads();
#pragma unroll
  for (int j = 0; j < 4; ++j)
    out[(size_t)(n0 + ty + j * 8) * K + k0 + tx] = f2bf(tile[tx][ty + j * 8]);
}

// ---------------- GEMM: C[M,N] = A[M,K](bf16) * Bt[N,K](bf16)^T + bias (+epilogue) ----
// EPI 0: bf16 out (+bias).  EPI 1: bf16 out, gelu(+bias).  EPI 2: f32 out, +bias+resid.
template<int EPI>
__global__ __launch_bounds__(256)
void gemm_bf16(const ushort* __restrict__ A, const ushort* __restrict__ Bt,
               const float* __restrict__ bias, const float* __restrict__ resid,
               void* __restrict__ outp, int M, int N, int K)
{
  __shared__ ushort As[128][40];   // +8 pad: breaks power-of-2 bank stride
  __shared__ ushort Bs[128][40];
  const int tid = threadIdx.x;
  const int lane = tid & 63, wave = tid >> 6;
  const int wm = wave >> 1, wn = wave & 1;
  const int grp = lane >> 4, r16 = lane & 15;
  const int bm = blockIdx.y * 128, bn = blockIdx.x * 128;
  const int srow = tid >> 1, schk = (tid & 1) * 16;   // 32 B per thread -> full 128x32 tile
  const ushort* pa = A + (size_t)(bm + srow) * K + schk;
  const ushort* pb = Bt + (size_t)(bn + srow) * K + schk;

  f32x4 acc[4][4] = {};

  for (int k0 = 0; k0 < K; k0 += 32) {
    const int4 av0 = *(const int4*)(pa + k0);
    const int4 av1 = *(const int4*)(pa + k0 + 8);
    const int4 bv0 = *(const int4*)(pb + k0);
    const int4 bv1 = *(const int4*)(pb + k0 + 8);
    __syncthreads();                       // prev-iter fragment reads done
    *(int4*)&As[srow][schk]     = av0;
    *(int4*)&As[srow][schk + 8] = av1;
    *(int4*)&Bs[srow][schk]     = bv0;
    *(int4*)&Bs[srow][schk + 8] = bv1;
    __syncthreads();
    bf16x8 af[4], bfr[4];
#pragma unroll
    for (int m = 0; m < 4; ++m)
      af[m] = *(const bf16x8*)&As[wm * 64 + m * 16 + r16][grp * 8];
#pragma unroll
    for (int n = 0; n < 4; ++n)
      bfr[n] = *(const bf16x8*)&Bs[wn * 64 + n * 16 + r16][grp * 8];
#pragma unroll
    for (int m = 0; m < 4; ++m)
#pragma unroll
      for (int n = 0; n < 4; ++n)
        acc[m][n] = __builtin_amdgcn_mfma_f32_16x16x32_bf16(af[m], bfr[n], acc[m][n], 0, 0, 0);
  }

#pragma unroll
  for (int n = 0; n < 4; ++n) {
    const int col = bn + wn * 64 + n * 16 + r16;
    const float bval = bias[col];
#pragma unroll
    for (int m = 0; m < 4; ++m) {
      const int row0 = bm + wm * 64 + m * 16 + grp * 4;
#pragma unroll
      for (int r = 0; r < 4; ++r) {
        const size_t idx = (size_t)(row0 + r) * N + col;
        float v = acc[m][n][r] + bval;
        if (EPI == 1) v = geluf(v);
        if (EPI == 2) ((float*)outp)[idx] = v + resid[idx];
        else          ((ushort*)outp)[idx] = f2bf(v);
      }
    }
  }
}

// ---------------- Causal flash attention ----------------
// qkv: [B*S, 3*D] bf16 (q at col h*64, k at 1024+h*64, v at 2048+h*64)
// out: [B*S, D] bf16 (heads concatenated)
// grid: (16 q-blocks of 64 rows, B*H=128). 4 waves; wave w owns q rows w*16..w*16+15.
__global__ __launch_bounds__(256)
void attn_kernel(const ushort* __restrict__ qkv, ushort* __restrict__ out)
{
  __shared__ ushort Ks[64][72];      // K tile  [kv][hd], pad 72
  __shared__ ushort Vt[64][72];      // V^T tile [hd][kv]
  __shared__ ushort Ps[4][16][72];   // per-wave P tile [q][kv]
  const int tid = threadIdx.x, lane = tid & 63, w = tid >> 6;
  const int grp = lane >> 4, r16 = lane & 15;
  const int qb = blockIdx.x, bh = blockIdx.y;
  const int b = bh >> 4, h = bh & 15;
  const size_t rowbase = (size_t)b * 1024;
  const int q0 = qb * 64 + w * 16;

  // Q fragments (A operand): row = r16, k(hd) = f*32 + grp*8 + j
  bf16x8 qf[2];
  {
    const ushort* qp = qkv + (rowbase + q0 + r16) * 3072 + h * 64;
    qf[0] = *(const bf16x8*)(qp + grp * 8);
    qf[1] = *(const bf16x8*)(qp + 32 + grp * 8);
  }

  f32x4 o[4] = {};
  float mrow[4] = {-1e30f, -1e30f, -1e30f, -1e30f};
  float lsum[4] = {0.f, 0.f, 0.f, 0.f};

  for (int kb = 0; kb <= qb; ++kb) {
    __syncthreads();                 // prev-iter LDS reads done
    // stage K tile and V^T tile (256 threads, 2 chunks of 8 bf16 each)
#pragma unroll
    for (int p = 0; p < 2; ++p) {
      const int c = p * 256 + tid;
      const int kv = c >> 3, hc = (c & 7) * 8;
      const ushort* kp = qkv + (rowbase + kb * 64 + kv) * 3072 + 1024 + h * 64 + hc;
      *(int4*)&Ks[kv][hc] = *(const int4*)kp;
      union { int4 v; ushort u[8]; } vv;
      vv.v = *(const int4*)(kp + 1024);
#pragma unroll
      for (int j = 0; j < 8; ++j) Vt[hc + j][kv] = vv.u[j];
    }
    __syncthreads();

    // S = Q K^T  (per wave: 16q x 64kv)
    f32x4 s[4] = {};
#pragma unroll
    for (int t = 0; t < 4; ++t) {
#pragma unroll
      for (int f = 0; f < 2; ++f) {
        const bf16x8 kf = *(const bf16x8*)&Ks[t * 16 + r16][f * 32 + grp * 8];
        s[t] = __builtin_amdgcn_mfma_f32_16x16x32_bf16(qf[f], kf, s[t], 0, 0, 0);
      }
    }
    // scale + causal mask (diagonal block only)
#pragma unroll
    for (int t = 0; t < 4; ++t)
#pragma unroll
      for (int r = 0; r < 4; ++r) {
        float v = s[t][r] * 0.125f;
        if (kb == qb && (t * 16 + r16) > (w * 16 + grp * 4 + r)) v = -1e30f;
        s[t][r] = v;
      }
    // online softmax (row r lives on the 16 lanes sharing grp)
    float fac[4];
#pragma unroll
    for (int r = 0; r < 4; ++r) {
      float mx = fmaxf(fmaxf(s[0][r], s[1][r]), fmaxf(s[2][r], s[3][r]));
#pragma unroll
      for (int msk = 1; msk < 16; msk <<= 1) mx = fmaxf(mx, __shfl_xor(mx, msk, 16));
      const float mn = fmaxf(mrow[r], mx);
      fac[r] = __expf(mrow[r] - mn);
      mrow[r] = mn;
      lsum[r] *= fac[r];
    }
#pragma unroll
    for (int t = 0; t < 4; ++t)
#pragma unroll
      for (int r = 0; r < 4; ++r) o[t][r] *= fac[r];
    float rsum[4] = {0.f, 0.f, 0.f, 0.f};
#pragma unroll
    for (int t = 0; t < 4; ++t)
#pragma unroll
      for (int r = 0; r < 4; ++r) {
        const float p = __expf(s[t][r] - mrow[r]);
        s[t][r] = p;
        rsum[r] += p;
      }
#pragma unroll
    for (int r = 0; r < 4; ++r) {
#pragma unroll
      for (int msk = 1; msk < 16; msk <<= 1) rsum[r] += __shfl_xor(rsum[r], msk, 16);
      lsum[r] += rsum[r];
    }
    // P -> LDS (C-layout -> A-fragment layout round trip)
#pragma unroll
    for (int t = 0; t < 4; ++t)
#pragma unroll
      for (int r = 0; r < 4; ++r)
        Ps[w][grp * 4 + r][t * 16 + r16] = f2bf(s[t][r]);
    __syncthreads();
    // O += P V
    bf16x8 pf[2];
    pf[0] = *(const bf16x8*)&Ps[w][r16][grp * 8];
    pf[1] = *(const bf16x8*)&Ps[w][r16][32 + grp * 8];
#pragma unroll
    for (int t = 0; t < 4; ++t) {
#pragma unroll
      for (int f = 0; f < 2; ++f) {
        const bf16x8 vf = *(const bf16x8*)&Vt[t * 16 + r16][f * 32 + grp * 8];
        o[t] = __builtin_amdgcn_mfma_f32_16x16x32_bf16(pf[f], vf, o[t], 0, 0, 0);
      }
    }
  }

  // normalize + store bf16 at [b, q, h*64 + hd]
  float inv[4];
#pragma unroll
  for (int r = 0; r < 4; ++r) inv[r] = 1.0f / lsum[r];
#pragma unroll
  for (int t = 0; t < 4; ++t)
#pragma unroll
    for (int r = 0; r < 4; ++r) {
      const int qrow = qb * 64 + w * 16 + grp * 4 + r;
      out[(rowbase + qrow) * 1024 + h * 64 + t * 16 + r16] = f2bf(o[t][r] * inv[r]);
    }
}

// ---------------- launch ----------------
extern "C" void kernel_launch(void* const* d_in, const int* in_sizes, int n_in,
                              void* d_out, int out_size, void* d_ws, size_t ws_size,
                              hipStream_t stream) {
  (void)in_sizes; (void)n_in; (void)out_size; (void)ws_size;
  const float* x     = (const float*)d_in[0];
  // d_in[1] = mask (causal; implemented analytically)
  const float* ln1_g = (const float*)d_in[2];
  const float* ln1_b = (const float*)d_in[3];
  const float* wqkv  = (const float*)d_in[4];
  const float* bqkv  = (const float*)d_in[5];
  const float* wo    = (const float*)d_in[6];
  const float* bo    = (const float*)d_in[7];
  const float* ln2_g = (const float*)d_in[8];
  const float* ln2_b = (const float*)d_in[9];
  const float* w1    = (const float*)d_in[10];
  const float* b1    = (const float*)d_in[11];
  const float* w2    = (const float*)d_in[12];
  const float* b2    = (const float*)d_in[13];
  float* out = (float*)d_out;
  char* ws = (char*)d_ws;

  // workspace layout (bytes)
  ushort* wqkvT = (ushort*)(ws + 0);          // [3072,1024] 6 MB
  ushort* woT   = (ushort*)(ws + 6291456);    // [1024,1024] 2 MB
  ushort* w1T   = (ushort*)(ws + 8388608);    // [4096,1024] 8 MB
  ushort* w2T   = (ushort*)(ws + 16777216);   // [1024,4096] 8 MB
  ushort* R1    = (ushort*)(ws + 25165824);   // 16 MB: h1 -> attn_out -> h2
  ushort* R2    = (ushort*)(ws + 41943040);   // 64 MB: qkv (48MB) -> gelu mid (64MB)

  const dim3 blk(256);
  tcvt_kernel<<<dim3(3072 / 32, 1024 / 32), blk, 0, stream>>>(wqkv, wqkvT, 1024, 3072);
  tcvt_kernel<<<dim3(1024 / 32, 1024 / 32), blk, 0, stream>>>(wo, woT, 1024, 1024);
  tcvt_kernel<<<dim3(4096 / 32, 1024 / 32), blk, 0, stream>>>(w1, w1T, 1024, 4096);
  tcvt_kernel<<<dim3(1024 / 32, 4096 / 32), blk, 0, stream>>>(w2, w2T, 4096, 1024);

  ln_bf16_kernel<<<8192, blk, 0, stream>>>(x, ln1_g, ln1_b, R1);
  gemm_bf16<0><<<dim3(3072 / 128, 8192 / 128), blk, 0, stream>>>(R1, wqkvT, bqkv, nullptr, R2, 8192, 3072, 1024);
  attn_kernel<<<dim3(16, 128), blk, 0, stream>>>(R2, R1);
  gemm_bf16<2><<<dim3(1024 / 128, 8192 / 128), blk, 0, stream>>>(R1, woT, bo, x, out, 8192, 1024, 1024);   // x2 -> d_out
  ln_bf16_kernel<<<8192, blk, 0, stream>>>(out, ln2_g, ln2_b, R1);
  gemm_bf16<1><<<dim3(4096 / 128, 8192 / 128), blk, 0, stream>>>(R1, w1T, b1, nullptr, R2, 8192, 4096, 1024);
  gemm_bf16<2><<<dim3(1024 / 128, 8192 / 128), blk, 0, stream>>>(R2, w2T, b2, out, out, 8192, 1024, 4096); // += x2
}

// Round 3
// 667.993 us; speedup vs baseline: 1.0149x; 1.0149x over previous
//
#include <hip/hip_runtime.h>

// TransformerBlock: B=8, S=1024, D=1024, H=16, HD=64
// LN1 -> QKV GEMM -> causal flash attn (K/V from L2, V pre-transposed)
//     -> proj(+resid) -> LN2 -> MLP1(+gelu) -> MLP2(+resid -> d_out)
// GEMMs: 128x128 tile, BK=64, global_load_lds(16B) + XOR-swizzled LDS (T2).

#define DEV static __device__ __forceinline__

typedef __attribute__((ext_vector_type(8))) __bf16 bf16x8;
typedef __attribute__((ext_vector_type(4))) float f32x4;

DEV ushort f2bf(float f) {
  union { float f; unsigned u; } c; c.f = f;
  unsigned r = (c.u + 0x7FFFu + ((c.u >> 16) & 1u)) >> 16;
  return (ushort)r;
}

DEV float geluf(float v) {
  return 0.5f * v * (1.0f + erff(v * 0.70710678118654752f));
}

DEV void gload16(const ushort* g, ushort* l) {
  __builtin_amdgcn_global_load_lds(
      (const __attribute__((address_space(1))) void*)g,
      (__attribute__((address_space(3))) void*)l, 16, 0, 0);
}

// ---------------- LayerNorm (f32 in -> bf16 out), one block per row ----------------
__global__ __launch_bounds__(256)
void ln_bf16_kernel(const float* __restrict__ x, const float* __restrict__ g,
                    const float* __restrict__ bb, ushort* __restrict__ out)
{
  const int row = blockIdx.x, tid = threadIdx.x;
  const float4 v = ((const float4*)x)[row * 256 + tid];
  float s = v.x + v.y + v.z + v.w;
  float sq = v.x * v.x + v.y * v.y + v.z * v.z + v.w * v.w;
#pragma unroll
  for (int off = 32; off >= 1; off >>= 1) {
    s += __shfl_xor(s, off, 64);
    sq += __shfl_xor(sq, off, 64);
  }
  __shared__ float ps[4], pq[4];
  if ((tid & 63) == 0) { ps[tid >> 6] = s; pq[tid >> 6] = sq; }
  __syncthreads();
  s = ps[0] + ps[1] + ps[2] + ps[3];
  sq = pq[0] + pq[1] + pq[2] + pq[3];
  const float mu = s * (1.0f / 1024.0f);
  const float rstd = rsqrtf(sq * (1.0f / 1024.0f) - mu * mu + 1e-5f);
  const float4 gv = ((const float4*)g)[tid];
  const float4 bv = ((const float4*)bb)[tid];
  ushort4 o;
  o.x = f2bf((v.x - mu) * rstd * gv.x + bv.x);
  o.y = f2bf((v.y - mu) * rstd * gv.y + bv.y);
  o.z = f2bf((v.z - mu) * rstd * gv.z + bv.z);
  o.w = f2bf((v.w - mu) * rstd * gv.w + bv.w);
  ((ushort4*)out)[row * 256 + tid] = o;
}

// ---------------- transpose + f32->bf16: out[n*K+k] = bf16(in[k*N+n]) ----------------
__global__ __launch_bounds__(256)
void tcvt_kernel(const float* __restrict__ in, ushort* __restrict__ out, int K, int N)
{
  __shared__ float tile[32][33];
  const int tx = threadIdx.x & 31, ty = threadIdx.x >> 5;  // ty 0..7
  const int n0 = blockIdx.x * 32, k0 = blockIdx.y * 32;
#pragma unroll
  for (int j = 0; j < 4; ++j)
    tile[ty + j * 8][tx] = in[(size_t)(k0 + ty + j * 8) * N + n0 + tx];
  __syncthreads();
#pragma unroll
  for (int j = 0; j < 4; ++j)
    out[(size_t)(n0 + ty + j * 8) * K + k0 + tx] = f2bf(tile[tx][ty + j * 8]);
}

// ---------------- V^T extraction: VT[(bh*64+hd)*1024 + s] = qkv[b,s, 2048+h*64+hd] ----
__global__ __launch_bounds__(256)
void vtr_kernel(const ushort* __restrict__ qkv, ushort* __restrict__ VT)
{
  __shared__ ushort tile[64][72];
  const int tid = threadIdx.x;
  const int bh = blockIdx.x, sb = blockIdx.y;
  const int b = bh >> 4, h = bh & 15;
  const int s0 = sb * 64;
#pragma unroll
  for (int it = 0; it < 2; ++it) {
    const int idx = it * 256 + tid;
    const int r = idx >> 3, hc = (idx & 7) * 8;
    *(int4*)&tile[r][hc] =
        *(const int4*)(qkv + ((size_t)b * 1024 + s0 + r) * 3072 + 2048 + h * 64 + hc);
  }
  __syncthreads();
#pragma unroll
  for (int it = 0; it < 2; ++it) {
    const int idx = it * 256 + tid;
    const int hd = idx >> 3, sc = (idx & 7) * 8;
    union { int4 v; ushort u[8]; } o;
#pragma unroll
    for (int j = 0; j < 8; ++j) o.u[j] = tile[sc + j][hd];
    *(int4*)(VT + ((size_t)bh * 64 + hd) * 1024 + s0 + sc) = o.v;
  }
}

// ---------------- GEMM: C[M,N] = A[M,K](bf16) * Bt[N,K](bf16)^T + bias (+epilogue) ----
// m97 structure: BK=64, global_load_lds 16B into linear LDS, XOR-swizzle (T2, rule 21):
//   LDS unit s of row r holds global k-unit s^(r&7); source lane pre-swizzle u=(lane&7)^(lane>>3).
// EPI 0: bf16 out (+bias).  EPI 1: bf16 out, gelu(+bias).  EPI 2: f32 out, +bias+resid.
template<int EPI>
__global__ __launch_bounds__(256)
void gemm_bf16(const ushort* __restrict__ A, const ushort* __restrict__ Bt,
               const float* __restrict__ bias, const float* __restrict__ resid,
               void* __restrict__ outp, int M, int N, int K)
{
  __shared__ ushort Asl[128 * 64];
  __shared__ ushort Bsl[128 * 64];
  const int tid = threadIdx.x;
  const int lane = tid & 63, w = tid >> 6;
  const int wm = w >> 1, wn = w & 1;
  const int grp = lane >> 4, r16 = lane & 15;
  const int bm = blockIdx.y * 128, bn = blockIdx.x * 128;

  // staging: wave w owns rows [w*32, w*32+32) in 4 chunks of 8 rows (1 KB each)
  const int lrow = lane >> 3;                      // 0..7
  const int uswz = ((lane & 7) ^ lrow) * 8;        // pre-swizzled k-unit (ushort offs)
  const ushort* pa = A  + (size_t)(bm + w * 32 + lrow) * K + uswz;
  const ushort* pb = Bt + (size_t)(bn + w * 32 + lrow) * K + uswz;

  f32x4 acc[4][4] = {};

  for (int k0 = 0; k0 < K; k0 += 64) {
    __syncthreads();                               // readers done with prev tile
#pragma unroll
    for (int i = 0; i < 4; ++i) {
      gload16(pa + (size_t)(i * 8) * K + k0, &Asl[(w * 32 + i * 8) * 64]);
      gload16(pb + (size_t)(i * 8) * K + k0, &Bsl[(w * 32 + i * 8) * 64]);
    }
    __syncthreads();                               // vmcnt(0) drained before barrier
#pragma unroll
    for (int ks = 0; ks < 2; ++ks) {
      bf16x8 af[4], bfr[4];
#pragma unroll
      for (int m = 0; m < 4; ++m) {
        const int r = wm * 64 + m * 16 + r16;
        af[m] = *(const bf16x8*)&Asl[r * 64 + ((ks * 4 + grp) ^ (r16 & 7)) * 8];
      }
#pragma unroll
      for (int n = 0; n < 4; ++n) {
        const int r = wn * 64 + n * 16 + r16;
        bfr[n] = *(const bf16x8*)&Bsl[r * 64 + ((ks * 4 + grp) ^ (r16 & 7)) * 8];
      }
#pragma unroll
      for (int m = 0; m < 4; ++m)
#pragma unroll
        for (int n = 0; n < 4; ++n)
          acc[m][n] = __builtin_amdgcn_mfma_f32_16x16x32_bf16(af[m], bfr[n], acc[m][n], 0, 0, 0);
    }
  }

#pragma unroll
  for (int n = 0; n < 4; ++n) {
    const int col = bn + wn * 64 + n * 16 + r16;
    const float bval = bias[col];
#pragma unroll
    for (int m = 0; m < 4; ++m) {
      const int row0 = bm + wm * 64 + m * 16 + grp * 4;
#pragma unroll
      for (int r = 0; r < 4; ++r) {
        const size_t idx = (size_t)(row0 + r) * N + col;
        float v = acc[m][n][r] + bval;
        if (EPI == 1) v = geluf(v);
        if (EPI == 2) ((float*)outp)[idx] = v + resid[idx];
        else          ((ushort*)outp)[idx] = f2bf(v);
      }
    }
  }
}

// ---------------- Causal flash attention (no K/V staging; V^T pre-materialized) -------
// qkv: [B*S, 3*D] bf16; VT: [B*H*64, 1024] bf16; out: [B*S, D] bf16
// grid (16 q-blocks of 64, B*H). 4 waves; wave w owns q rows w*16..w*16+15. No barriers.
__global__ __launch_bounds__(256)
void attn_kernel(const ushort* __restrict__ qkv, const ushort* __restrict__ VT,
                 ushort* __restrict__ out)
{
  __shared__ ushort Ps[4][16][72];   // per-wave P tile [q][kv]
  const int tid = threadIdx.x, lane = tid & 63, w = tid >> 6;
  const int grp = lane >> 4, r16 = lane & 15;
  const int qb = blockIdx.x, bh = blockIdx.y;
  const int b = bh >> 4, h = bh & 15;
  const size_t rowbase = (size_t)b * 1024;
  const int q0 = qb * 64 + w * 16;

  // Q fragments (A operand): row = r16, k(hd) = f*32 + grp*8 + j
  bf16x8 qf[2];
  {
    const ushort* qp = qkv + (rowbase + q0 + r16) * 3072 + h * 64;
    qf[0] = *(const bf16x8*)(qp + grp * 8);
    qf[1] = *(const bf16x8*)(qp + 32 + grp * 8);
  }
  const ushort* kbase = qkv + rowbase * 3072 + 1024 + h * 64;   // + s*3072
  const ushort* vbase = VT + (size_t)bh * 64 * 1024;            // + hd*1024

  f32x4 o[4] = {};
  float mrow[4] = {-1e30f, -1e30f, -1e30f, -1e30f};
  float lsum[4] = {0.f, 0.f, 0.f, 0.f};

  for (int kb = 0; kb <= qb; ++kb) {
    // S = Q K^T  (B-fragment: col j = kv = t*16+r16, k = hd contiguous)
    f32x4 s[4] = {};
#pragma unroll
    for (int t = 0; t < 4; ++t) {
#pragma unroll
      for (int f = 0; f < 2; ++f) {
        const bf16x8 kf = *(const bf16x8*)(kbase +
            (size_t)(kb * 64 + t * 16 + r16) * 3072 + f * 32 + grp * 8);
        s[t] = __builtin_amdgcn_mfma_f32_16x16x32_bf16(qf[f], kf, s[t], 0, 0, 0);
      }
    }
    // scale + causal mask (diagonal block only)
#pragma unroll
    for (int t = 0; t < 4; ++t)
#pragma unroll
      for (int r = 0; r < 4; ++r) {
        float v = s[t][r] * 0.125f;
        if (kb == qb && (t * 16 + r16) > (w * 16 + grp * 4 + r)) v = -1e30f;
        s[t][r] = v;
      }
    // online softmax (row r lives on the 16 lanes sharing grp)
    float fac[4];
#pragma unroll
    for (int r = 0; r < 4; ++r) {
      float mx = fmaxf(fmaxf(s[0][r], s[1][r]), fmaxf(s[2][r], s[3][r]));
#pragma unroll
      for (int msk = 1; msk < 16; msk <<= 1) mx = fmaxf(mx, __shfl_xor(mx, msk, 16));
      const float mn = fmaxf(mrow[r], mx);
      fac[r] = __expf(mrow[r] - mn);
      mrow[r] = mn;
      lsum[r] *= fac[r];
    }
#pragma unroll
    for (int t = 0; t < 4; ++t)
#pragma unroll
      for (int r = 0; r < 4; ++r) o[t][r] *= fac[r];
    float rsum[4] = {0.f, 0.f, 0.f, 0.f};
#pragma unroll
    for (int t = 0; t < 4; ++t)
#pragma unroll
      for (int r = 0; r < 4; ++r) {
        const float p = __expf(s[t][r] - mrow[r]);
        s[t][r] = p;
        rsum[r] += p;
      }
#pragma unroll
    for (int r = 0; r < 4; ++r) {
#pragma unroll
      for (int msk = 1; msk < 16; msk <<= 1) rsum[r] += __shfl_xor(rsum[r], msk, 16);
      lsum[r] += rsum[r];
    }
    // P: C-layout -> A-fragment layout round trip (per-wave LDS, in-order, no barrier)
#pragma unroll
    for (int t = 0; t < 4; ++t)
#pragma unroll
      for (int r = 0; r < 4; ++r)
        Ps[w][grp * 4 + r][t * 16 + r16] = f2bf(s[t][r]);
    bf16x8 pf[2];
    pf[0] = *(const bf16x8*)&Ps[w][r16][grp * 8];
    pf[1] = *(const bf16x8*)&Ps[w][r16][32 + grp * 8];
    // O += P V  (B-fragment: col j = hd = t*16+r16, k = kv contiguous from VT)
#pragma unroll
    for (int t = 0; t < 4; ++t) {
#pragma unroll
      for (int f = 0; f < 2; ++f) {
        const bf16x8 vf = *(const bf16x8*)(vbase +
            (size_t)(t * 16 + r16) * 1024 + kb * 64 + f * 32 + grp * 8);
        o[t] = __builtin_amdgcn_mfma_f32_16x16x32_bf16(pf[f], vf, o[t], 0, 0, 0);
      }
    }
  }

  // normalize + store bf16 at [b, q, h*64 + hd]
  float inv[4];
#pragma unroll
  for (int r = 0; r < 4; ++r) inv[r] = 1.0f / lsum[r];
#pragma unroll
  for (int t = 0; t < 4; ++t)
#pragma unroll
    for (int r = 0; r < 4; ++r) {
      const int qrow = qb * 64 + w * 16 + grp * 4 + r;
      out[(rowbase + qrow) * 1024 + h * 64 + t * 16 + r16] = f2bf(o[t][r] * inv[r]);
    }
}

// ---------------- launch ----------------
extern "C" void kernel_launch(void* const* d_in, const int* in_sizes, int n_in,
                              void* d_out, int out_size, void* d_ws, size_t ws_size,
                              hipStream_t stream) {
  (void)in_sizes; (void)n_in; (void)out_size; (void)ws_size;
  const float* x     = (const float*)d_in[0];
  // d_in[1] = mask (causal; implemented analytically)
  const float* ln1_g = (const float*)d_in[2];
  const float* ln1_b = (const float*)d_in[3];
  const float* wqkv  = (const float*)d_in[4];
  const float* bqkv  = (const float*)d_in[5];
  const float* wo    = (const float*)d_in[6];
  const float* bo    = (const float*)d_in[7];
  const float* ln2_g = (const float*)d_in[8];
  const float* ln2_b = (const float*)d_in[9];
  const float* w1    = (const float*)d_in[10];
  const float* b1    = (const float*)d_in[11];
  const float* w2    = (const float*)d_in[12];
  const float* b2    = (const float*)d_in[13];
  float* out = (float*)d_out;
  char* ws = (char*)d_ws;

  // workspace layout (bytes)
  ushort* wqkvT = (ushort*)(ws + 0);          // [3072,1024] 6 MB
  ushort* woT   = (ushort*)(ws + 6291456);    // [1024,1024] 2 MB
  ushort* w1T   = (ushort*)(ws + 8388608);    // [4096,1024] 8 MB
  ushort* w2T   = (ushort*)(ws + 16777216);   // [1024,4096] 8 MB
  ushort* R1    = (ushort*)(ws + 25165824);   // 16 MB: h1 -> attn_out -> h2
  ushort* R2    = (ushort*)(ws + 41943040);   // 64 MB: qkv (48MB) -> gelu mid (64MB)
  ushort* VT    = (ushort*)(ws + 41943040 + 50331648);  // 16 MB, dead zone of R2 during attn

  const dim3 blk(256);
  tcvt_kernel<<<dim3(3072 / 32, 1024 / 32), blk, 0, stream>>>(wqkv, wqkvT, 1024, 3072);
  tcvt_kernel<<<dim3(1024 / 32, 1024 / 32), blk, 0, stream>>>(wo, woT, 1024, 1024);
  tcvt_kernel<<<dim3(4096 / 32, 1024 / 32), blk, 0, stream>>>(w1, w1T, 1024, 4096);
  tcvt_kernel<<<dim3(1024 / 32, 4096 / 32), blk, 0, stream>>>(w2, w2T, 4096, 1024);

  ln_bf16_kernel<<<8192, blk, 0, stream>>>(x, ln1_g, ln1_b, R1);
  gemm_bf16<0><<<dim3(3072 / 128, 8192 / 128), blk, 0, stream>>>(R1, wqkvT, bqkv, nullptr, R2, 8192, 3072, 1024);
  vtr_kernel<<<dim3(128, 16), blk, 0, stream>>>(R2, VT);
  attn_kernel<<<dim3(16, 128), blk, 0, stream>>>(R2, VT, R1);
  gemm_bf16<2><<<dim3(1024 / 128, 8192 / 128), blk, 0, stream>>>(R1, woT, bo, x, out, 8192, 1024, 1024);   // x2 -> d_out
  ln_bf16_kernel<<<8192, blk, 0, stream>>>(out, ln2_g, ln2_b, R1);
  gemm_bf16<1><<<dim3(4096 / 128, 8192 / 128), blk, 0, stream>>>(R1, w1T, b1, nullptr, R2, 8192, 4096, 1024);
  gemm_bf16<2><<<dim3(1024 / 128, 8192 / 128), blk, 0, stream>>>(R2, w2T, b2, out, out, 8192, 1024, 4096); // += x2
}

// Round 6
// 551.083 us; speedup vs baseline: 1.2302x; 1.2121x over previous
//
#include <hip/hip_runtime.h>

// TransformerBlock: B=8, S=1024, D=1024, H=16, HD=64
// LN1 -> QKV GEMM -> causal flash attn (LDS-staged K/V^T via global_load_lds + XOR swizzle)
//     -> proj(+resid) -> LN2 -> MLP1(+gelu) -> MLP2(+resid -> d_out)
// GEMMs: 128x128 tile, BK=64, global_load_lds(16B) + XOR-swizzled LDS (T2).

#define DEV static __device__ __forceinline__

typedef __attribute__((ext_vector_type(8))) __bf16 bf16x8;
typedef __attribute__((ext_vector_type(4))) float f32x4;

DEV ushort f2bf(float f) {
  union { float f; unsigned u; } c; c.f = f;
  unsigned r = (c.u + 0x7FFFu + ((c.u >> 16) & 1u)) >> 16;
  return (ushort)r;
}

DEV float geluf(float v) {
  return 0.5f * v * (1.0f + erff(v * 0.70710678118654752f));
}

DEV void gload16(const ushort* g, ushort* l) {
  __builtin_amdgcn_global_load_lds(
      (const __attribute__((address_space(1))) void*)g,
      (__attribute__((address_space(3))) void*)l, 16, 0, 0);
}

// ---------------- LayerNorm (f32 in -> bf16 out), one block per row ----------------
__global__ __launch_bounds__(256)
void ln_bf16_kernel(const float* __restrict__ x, const float* __restrict__ g,
                    const float* __restrict__ bb, ushort* __restrict__ out)
{
  const int row = blockIdx.x, tid = threadIdx.x;
  const float4 v = ((const float4*)x)[row * 256 + tid];
  float s = v.x + v.y + v.z + v.w;
  float sq = v.x * v.x + v.y * v.y + v.z * v.z + v.w * v.w;
#pragma unroll
  for (int off = 32; off >= 1; off >>= 1) {
    s += __shfl_xor(s, off, 64);
    sq += __shfl_xor(sq, off, 64);
  }
  __shared__ float ps[4], pq[4];
  if ((tid & 63) == 0) { ps[tid >> 6] = s; pq[tid >> 6] = sq; }
  __syncthreads();
  s = ps[0] + ps[1] + ps[2] + ps[3];
  sq = pq[0] + pq[1] + pq[2] + pq[3];
  const float mu = s * (1.0f / 1024.0f);
  const float rstd = rsqrtf(sq * (1.0f / 1024.0f) - mu * mu + 1e-5f);
  const float4 gv = ((const float4*)g)[tid];
  const float4 bv = ((const float4*)bb)[tid];
  ushort4 o;
  o.x = f2bf((v.x - mu) * rstd * gv.x + bv.x);
  o.y = f2bf((v.y - mu) * rstd * gv.y + bv.y);
  o.z = f2bf((v.z - mu) * rstd * gv.z + bv.z);
  o.w = f2bf((v.w - mu) * rstd * gv.w + bv.w);
  ((ushort4*)out)[row * 256 + tid] = o;
}

// ---------------- transpose + f32->bf16: out[n*K+k] = bf16(in[k*N+n]) ----------------
__global__ __launch_bounds__(256)
void tcvt_kernel(const float* __restrict__ in, ushort* __restrict__ out, int K, int N)
{
  __shared__ float tile[32][33];
  const int tx = threadIdx.x & 31, ty = threadIdx.x >> 5;  // ty 0..7
  const int n0 = blockIdx.x * 32, k0 = blockIdx.y * 32;
#pragma unroll
  for (int j = 0; j < 4; ++j)
    tile[ty + j * 8][tx] = in[(size_t)(k0 + ty + j * 8) * N + n0 + tx];
  __syncthreads();
#pragma unroll
  for (int j = 0; j < 4; ++j)
    out[(size_t)(n0 + ty + j * 8) * K + k0 + tx] = f2bf(tile[tx][ty + j * 8]);
}

// ---------------- V^T extraction: VT[(bh*64+hd)*1024 + s] = qkv[b,s, 2048+h*64+hd] ----
__global__ __launch_bounds__(256)
void vtr_kernel(const ushort* __restrict__ qkv, ushort* __restrict__ VT)
{
  __shared__ ushort tile[64][72];
  const int tid = threadIdx.x;
  const int bh = blockIdx.x, sb = blockIdx.y;
  const int b = bh >> 4, h = bh & 15;
  const int s0 = sb * 64;
#pragma unroll
  for (int it = 0; it < 2; ++it) {
    const int idx = it * 256 + tid;
    const int r = idx >> 3, hc = (idx & 7) * 8;
    *(int4*)&tile[r][hc] =
        *(const int4*)(qkv + ((size_t)b * 1024 + s0 + r) * 3072 + 2048 + h * 64 + hc);
  }
  __syncthreads();
#pragma unroll
  for (int it = 0; it < 2; ++it) {
    const int idx = it * 256 + tid;
    const int hd = idx >> 3, sc = (idx & 7) * 8;
    union { int4 v; ushort u[8]; } o;
#pragma unroll
    for (int j = 0; j < 8; ++j) o.u[j] = tile[sc + j][hd];
    *(int4*)(VT + ((size_t)bh * 64 + hd) * 1024 + s0 + sc) = o.v;
  }
}

// ---------------- GEMM: C[M,N] = A[M,K](bf16) * Bt[N,K](bf16)^T + bias (+epilogue) ----
// m97 structure: BK=64, global_load_lds 16B into linear LDS, XOR-swizzle (T2, rule 21):
//   LDS unit s of row r holds global k-unit s^(r&7); source lane pre-swizzle u=(lane&7)^(lane>>3).
// EPI 0: bf16 out (+bias).  EPI 1: bf16 out, gelu(+bias).  EPI 2: f32 out, +bias+resid.
template<int EPI>
__global__ __launch_bounds__(256)
void gemm_bf16(const ushort* __restrict__ A, const ushort* __restrict__ Bt,
               const float* __restrict__ bias, const float* __restrict__ resid,
               void* __restrict__ outp, int M, int N, int K)
{
  __shared__ ushort Asl[128 * 64];
  __shared__ ushort Bsl[128 * 64];
  const int tid = threadIdx.x;
  const int lane = tid & 63, w = tid >> 6;
  const int wm = w >> 1, wn = w & 1;
  const int grp = lane >> 4, r16 = lane & 15;
  const int bm = blockIdx.y * 128, bn = blockIdx.x * 128;

  // staging: wave w owns rows [w*32, w*32+32) in 4 chunks of 8 rows (1 KB each)
  const int lrow = lane >> 3;                      // 0..7
  const int uswz = ((lane & 7) ^ lrow) * 8;        // pre-swizzled k-unit (ushort offs)
  const ushort* pa = A  + (size_t)(bm + w * 32 + lrow) * K + uswz;
  const ushort* pb = Bt + (size_t)(bn + w * 32 + lrow) * K + uswz;

  f32x4 acc[4][4] = {};

  for (int k0 = 0; k0 < K; k0 += 64) {
    __syncthreads();                               // readers done with prev tile
#pragma unroll
    for (int i = 0; i < 4; ++i) {
      gload16(pa + (size_t)(i * 8) * K + k0, &Asl[(w * 32 + i * 8) * 64]);
      gload16(pb + (size_t)(i * 8) * K + k0, &Bsl[(w * 32 + i * 8) * 64]);
    }
    __syncthreads();                               // vmcnt(0) drained before barrier
#pragma unroll
    for (int ks = 0; ks < 2; ++ks) {
      bf16x8 af[4], bfr[4];
#pragma unroll
      for (int m = 0; m < 4; ++m) {
        const int r = wm * 64 + m * 16 + r16;
        af[m] = *(const bf16x8*)&Asl[r * 64 + ((ks * 4 + grp) ^ (r16 & 7)) * 8];
      }
#pragma unroll
      for (int n = 0; n < 4; ++n) {
        const int r = wn * 64 + n * 16 + r16;
        bfr[n] = *(const bf16x8*)&Bsl[r * 64 + ((ks * 4 + grp) ^ (r16 & 7)) * 8];
      }
#pragma unroll
      for (int m = 0; m < 4; ++m)
#pragma unroll
        for (int n = 0; n < 4; ++n)
          acc[m][n] = __builtin_amdgcn_mfma_f32_16x16x32_bf16(af[m], bfr[n], acc[m][n], 0, 0, 0);
    }
  }

#pragma unroll
  for (int n = 0; n < 4; ++n) {
    const int col = bn + wn * 64 + n * 16 + r16;
    const float bval = bias[col];
#pragma unroll
    for (int m = 0; m < 4; ++m) {
      const int row0 = bm + wm * 64 + m * 16 + grp * 4;
#pragma unroll
      for (int r = 0; r < 4; ++r) {
        const size_t idx = (size_t)(row0 + r) * N + col;
        float v = acc[m][n][r] + bval;
        if (EPI == 1) v = geluf(v);
        if (EPI == 2) ((float*)outp)[idx] = v + resid[idx];
        else          ((ushort*)outp)[idx] = f2bf(v);
      }
    }
  }
}

// ---------------- Causal flash attention ----------------
// qkv: [B*S, 3*D] bf16; VT: [B*H*64, 1024] bf16; out: [B*S, D] bf16
// grid (16 q-blocks of 64, B*H). 4 waves; wave w owns q rows w*16..w*16+15.
// K tile [kv][hd] and V^T tile [hd][kv] staged via global_load_lds with the
// GEMM's both-sides XOR swizzle (linear LDS dest, pre-swizzled global source).
__global__ __launch_bounds__(256)
void attn_kernel(const ushort* __restrict__ qkv, const ushort* __restrict__ VT,
                 ushort* __restrict__ out)
{
  __shared__ ushort Ks[64 * 64];     // [kv][hd units swizzled]
  __shared__ ushort Vs[64 * 64];     // [hd][kv units swizzled]
  __shared__ ushort Ps[4][16][72];   // per-wave P tile [q][kv]
  const int tid = threadIdx.x, lane = tid & 63, w = tid >> 6;
  const int grp = lane >> 4, r16 = lane & 15;
  const int qb = 15 - blockIdx.x;    // heavy blocks first
  const int bh = blockIdx.y;
  const int b = bh >> 4, h = bh & 15;
  const size_t rowbase = (size_t)b * 1024;
  const int q0 = qb * 64 + w * 16;

  // Q fragments (A operand): row = r16, k(hd) = f*32 + grp*8 + j
  bf16x8 qf[2];
  {
    const ushort* qp = qkv + (rowbase + q0 + r16) * 3072 + h * 64;
    qf[0] = *(const bf16x8*)(qp + grp * 8);
    qf[1] = *(const bf16x8*)(qp + 32 + grp * 8);
  }

  // staging pointers: wave w stages rows [w*16, w*16+16) of each tile
  const int lrow = lane >> 3;                     // 0..7
  const int uswz = ((lane & 7) ^ lrow) * 8;       // pre-swizzled unit (ushort offs)
  const ushort* kstg = qkv + (rowbase + w * 16 + lrow) * 3072 + 1024 + h * 64 + uswz; // + kv*3072
  const ushort* vstg = VT + ((size_t)bh * 64 + w * 16 + lrow) * 1024 + uswz;          // + kb*64

  f32x4 o[4] = {};
  float mrow[4] = {-1e30f, -1e30f, -1e30f, -1e30f};
  float lsum[4] = {0.f, 0.f, 0.f, 0.f};

  for (int kb = 0; kb <= qb; ++kb) {
    __syncthreads();                 // readers done with prev tile
#pragma unroll
    for (int i = 0; i < 2; ++i) {
      gload16(kstg + (size_t)(kb * 64 + i * 8) * 3072, &Ks[(w * 16 + i * 8) * 64]);
      gload16(vstg + (size_t)(i * 8) * 1024 + kb * 64, &Vs[(w * 16 + i * 8) * 64]);
    }
    __syncthreads();                 // staged (vmcnt drained before barrier)

    // S = Q K^T  (B-fragment: col j = kv = t*16+r16, k = hd)
    f32x4 s[4] = {};
#pragma unroll
    for (int t = 0; t < 4; ++t) {
      const int r = t * 16 + r16;
#pragma unroll
      for (int f = 0; f < 2; ++f) {
        const bf16x8 kf = *(const bf16x8*)&Ks[r * 64 + ((f * 4 + grp) ^ (r16 & 7)) * 8];
        s[t] = __builtin_amdgcn_mfma_f32_16x16x32_bf16(qf[f], kf, s[t], 0, 0, 0);
      }
    }
    // scale + causal mask (diagonal block only)
#pragma unroll
    for (int t = 0; t < 4; ++t)
#pragma unroll
      for (int r = 0; r < 4; ++r) {
        float v = s[t][r] * 0.125f;
        if (kb == qb && (t * 16 + r16) > (w * 16 + grp * 4 + r)) v = -1e30f;
        s[t][r] = v;
      }
    // online softmax (row r lives on the 16 lanes sharing grp)
    float fac[4];
#pragma unroll
    for (int r = 0; r < 4; ++r) {
      float mx = fmaxf(fmaxf(s[0][r], s[1][r]), fmaxf(s[2][r], s[3][r]));
#pragma unroll
      for (int msk = 1; msk < 16; msk <<= 1) mx = fmaxf(mx, __shfl_xor(mx, msk, 16));
      const float mn = fmaxf(mrow[r], mx);
      fac[r] = __expf(mrow[r] - mn);
      mrow[r] = mn;
      lsum[r] *= fac[r];
    }
#pragma unroll
    for (int t = 0; t < 4; ++t)
#pragma unroll
      for (int r = 0; r < 4; ++r) o[t][r] *= fac[r];
    float rsum[4] = {0.f, 0.f, 0.f, 0.f};
#pragma unroll
    for (int t = 0; t < 4; ++t)
#pragma unroll
      for (int r = 0; r < 4; ++r) {
        const float p = __expf(s[t][r] - mrow[r]);
        s[t][r] = p;
        rsum[r] += p;
      }
#pragma unroll
    for (int r = 0; r < 4; ++r) {
#pragma unroll
      for (int msk = 1; msk < 16; msk <<= 1) rsum[r] += __shfl_xor(rsum[r], msk, 16);
      lsum[r] += rsum[r];
    }
    // P: C-layout -> A-fragment layout round trip (per-wave LDS, in-order within wave)
#pragma unroll
    for (int t = 0; t < 4; ++t)
#pragma unroll
      for (int r = 0; r < 4; ++r)
        Ps[w][grp * 4 + r][t * 16 + r16] = f2bf(s[t][r]);
    bf16x8 pf[2];
    pf[0] = *(const bf16x8*)&Ps[w][r16][grp * 8];
    pf[1] = *(const bf16x8*)&Ps[w][r16][32 + grp * 8];
    // O += P V  (B-fragment: col j = hd = t*16+r16, k = kv)
#pragma unroll
    for (int t = 0; t < 4; ++t) {
      const int r = t * 16 + r16;
#pragma unroll
      for (int f = 0; f < 2; ++f) {
        const bf16x8 vf = *(const bf16x8*)&Vs[r * 64 + ((f * 4 + grp) ^ (r16 & 7)) * 8];
        o[t] = __builtin_amdgcn_mfma_f32_16x16x32_bf16(pf[f], vf, o[t], 0, 0, 0);
      }
    }
  }

  // normalize + store bf16 at [b, q, h*64 + hd]
  float inv[4];
#pragma unroll
  for (int r = 0; r < 4; ++r) inv[r] = 1.0f / lsum[r];
#pragma unroll
  for (int t = 0; t < 4; ++t)
#pragma unroll
    for (int r = 0; r < 4; ++r) {
      const int qrow = qb * 64 + w * 16 + grp * 4 + r;
      out[(rowbase + qrow) * 1024 + h * 64 + t * 16 + r16] = f2bf(o[t][r] * inv[r]);
    }
}

// ---------------- launch ----------------
extern "C" void kernel_launch(void* const* d_in, const int* in_sizes, int n_in,
                              void* d_out, int out_size, void* d_ws, size_t ws_size,
                              hipStream_t stream) {
  (void)in_sizes; (void)n_in; (void)out_size; (void)ws_size;
  const float* x     = (const float*)d_in[0];
  // d_in[1] = mask (causal; implemented analytically)
  const float* ln1_g = (const float*)d_in[2];
  const float* ln1_b = (const float*)d_in[3];
  const float* wqkv  = (const float*)d_in[4];
  const float* bqkv  = (const float*)d_in[5];
  const float* wo    = (const float*)d_in[6];
  const float* bo    = (const float*)d_in[7];
  const float* ln2_g = (const float*)d_in[8];
  const float* ln2_b = (const float*)d_in[9];
  const float* w1    = (const float*)d_in[10];
  const float* b1    = (const float*)d_in[11];
  const float* w2    = (const float*)d_in[12];
  const float* b2    = (const float*)d_in[13];
  float* out = (float*)d_out;
  char* ws = (char*)d_ws;

  // workspace layout (bytes)
  ushort* wqkvT = (ushort*)(ws + 0);          // [3072,1024] 6 MB
  ushort* woT   = (ushort*)(ws + 6291456);    // [1024,1024] 2 MB
  ushort* w1T   = (ushort*)(ws + 8388608);    // [4096,1024] 8 MB
  ushort* w2T   = (ushort*)(ws + 16777216);   // [1024,4096] 8 MB
  ushort* R1    = (ushort*)(ws + 25165824);   // 16 MB: h1 -> attn_out -> h2
  ushort* R2    = (ushort*)(ws + 41943040);   // 64 MB: qkv (48MB) -> gelu mid (64MB)
  ushort* VT    = (ushort*)(ws + 41943040 + 50331648);  // 16 MB, dead zone of R2 during attn

  const dim3 blk(256);
  tcvt_kernel<<<dim3(3072 / 32, 1024 / 32), blk, 0, stream>>>(wqkv, wqkvT, 1024, 3072);
  tcvt_kernel<<<dim3(1024 / 32, 1024 / 32), blk, 0, stream>>>(wo, woT, 1024, 1024);
  tcvt_kernel<<<dim3(4096 / 32, 1024 / 32), blk, 0, stream>>>(w1, w1T, 1024, 4096);
  tcvt_kernel<<<dim3(1024 / 32, 4096 / 32), blk, 0, stream>>>(w2, w2T, 4096, 1024);

  ln_bf16_kernel<<<8192, blk, 0, stream>>>(x, ln1_g, ln1_b, R1);
  gemm_bf16<0><<<dim3(3072 / 128, 8192 / 128), blk, 0, stream>>>(R1, wqkvT, bqkv, nullptr, R2, 8192, 3072, 1024);
  vtr_kernel<<<dim3(128, 16), blk, 0, stream>>>(R2, VT);
  attn_kernel<<<dim3(16, 128), blk, 0, stream>>>(R2, VT, R1);
  gemm_bf16<2><<<dim3(1024 / 128, 8192 / 128), blk, 0, stream>>>(R1, woT, bo, x, out, 8192, 1024, 1024);   // x2 -> d_out
  ln_bf16_kernel<<<8192, blk, 0, stream>>>(out, ln2_g, ln2_b, R1);
  gemm_bf16<1><<<dim3(4096 / 128, 8192 / 128), blk, 0, stream>>>(R1, w1T, b1, nullptr, R2, 8192, 4096, 1024);
  gemm_bf16<2><<<dim3(1024 / 128, 8192 / 128), blk, 0, stream>>>(R2, w2T, b2, out, out, 8192, 1024, 4096); // += x2
}